// Round 7
// baseline (524.007 us; speedup 1.0000x reference)
//
#include <hip/hip_runtime.h>
#include <hip/hip_bf16.h>
#include <stdint.h>
#include <stddef.h>

typedef _Float16 half2_t __attribute__((ext_vector_type(2)));
typedef _Float16 f16x8 __attribute__((ext_vector_type(8)));
typedef float f32x4 __attribute__((ext_vector_type(4)));

// ---------------- param_net stage 1: partial h = X @ W1 (K-split) ----------
__global__ __launch_bounds__(128) void k_paramnet1(
    const float* __restrict__ X, const float* __restrict__ W1,
    float* __restrict__ hpart) {
  const int j = threadIdx.x;
  const int ks = blockIdx.x;
  const int b0 = blockIdx.y * 32;

  float w1r[128];
#pragma unroll
  for (int k = 0; k < 128; ++k)
    w1r[k] = W1[(size_t)(ks * 128 + k) * 128 + j];

  for (int bb = 0; bb < 32; ++bb) {
    const float* xr = X + (size_t)(b0 + bb) * 4096 + ks * 128;
    float a0 = 0.f, a1 = 0.f, a2 = 0.f, a3 = 0.f;
#pragma unroll
    for (int k = 0; k < 128; k += 4) {
      a0 = fmaf(w1r[k + 0], xr[k + 0], a0);
      a1 = fmaf(w1r[k + 1], xr[k + 1], a1);
      a2 = fmaf(w1r[k + 2], xr[k + 2], a2);
      a3 = fmaf(w1r[k + 3], xr[k + 3], a3);
    }
    hpart[((size_t)ks * 512 + (b0 + bb)) * 128 + j] = (a0 + a1) + (a2 + a3);
  }
}

// ---- fused: h-reduce + relu (was k_paramnet2) + W2 matvec + sigmoids ------
__global__ __launch_bounds__(256) void k_params_state(
    const float* __restrict__ hpart, const float* __restrict__ b1,
    const float* __restrict__ W2, const float* __restrict__ b2,
    const float* __restrict__ X,
    float* __restrict__ betaW, float* __restrict__ sigmaW,
    float* __restrict__ gammaW, float* __restrict__ S0W,
    float* __restrict__ E0W, float* __restrict__ I0W,
    float* __restrict__ stats) {
  const int b0 = blockIdx.x * 2;
  const int t = threadIdx.x;
  __shared__ float hs[256];  // hs[bb*128 + j]
  {
    const int bb = t >> 7, j = t & 127;
    float s = b1[j];
    const float* hp = hpart + (size_t)(b0 + bb) * 128 + j;
#pragma unroll
    for (int ks = 0; ks < 32; ++ks) s += hp[(size_t)ks * 65536];
    hs[t] = fmaxf(s, 0.f);
  }
  __syncthreads();

  float a00 = b2[t], a01 = b2[256 + t], a02 = b2[512 + t], a03 = b2[768 + t];
  float a10 = a00, a11 = a01, a12 = a02, a13 = a03;
#pragma unroll 2
  for (int k = 0; k < 128; ++k) {
    const float* wr = W2 + (size_t)k * 1024;
    const float w0 = wr[t], w1 = wr[256 + t], w2 = wr[512 + t], w3 = wr[768 + t];
    const float hv0 = hs[k], hv1 = hs[128 + k];
    a00 = fmaf(hv0, w0, a00); a01 = fmaf(hv0, w1, a01);
    a02 = fmaf(hv0, w2, a02); a03 = fmaf(hv0, w3, a03);
    a10 = fmaf(hv1, w0, a10); a11 = fmaf(hv1, w1, a11);
    a12 = fmaf(hv1, w2, a12); a13 = fmaf(hv1, w3, a13);
  }
  float bsum = 0.f, ssum = 0.f, gsum = 0.f;
#pragma unroll
  for (int j = 0; j < 2; ++j) {
    const float p0 = j ? a10 : a00, p1 = j ? a11 : a01;
    const float p2 = j ? a12 : a02, p3 = j ? a13 : a03;
    const float beta = 3.f / (1.f + __expf(-p0));
    const float sig  = 1.f / (1.f + __expf(-p1));
    const float gam  = 1.f / (1.f + __expf(-p2));
    const float e0r  = 5.f / (1.f + __expf(-p3));
    const int base = (b0 + j) * 256 + t;
    const float I0 = fmaxf(X[(size_t)(b0 + j) * 4096 + 15 * 256 + t], 1e-6f);
    const float E0 = I0 * e0r;
    const float S0 = fmaxf(1.f - E0 - I0, 0.01f);
    betaW[base] = beta; sigmaW[base] = sig; gammaW[base] = gam;
    S0W[base] = S0; E0W[base] = E0; I0W[base] = I0;
    bsum += beta; ssum += sig; gsum += gam;
  }
  atomicAdd(stats + t, bsum);
  atomicAdd(stats + 256 + t, ssum);
  atomicAdd(stats + 512 + t, gsum);
}

// ---------------- mobility stage 1: hm = relu(cnn @ M1 + mb1) as f16 -------
__global__ __launch_bounds__(128) void k_mobility1(
    const float* __restrict__ cnn, const float* __restrict__ M1,
    const float* __restrict__ mb1, _Float16* __restrict__ hmf) {
  const int b = blockIdx.x, j = threadIdx.x;
  const float* cr = cnn + b * 64;
  float a = mb1[j];
#pragma unroll
  for (int k = 0; k < 64; ++k) a = fmaf(cr[k], M1[k * 128 + j], a);
  hmf[b * 128 + j] = (_Float16)fmaxf(a, 0.f);
}

// ---------------- transpose M2 -> M2T[n][m][k] f16, LDS-tiled --------------
__global__ __launch_bounds__(256) void k_cvtM2(
    const float* __restrict__ M2, _Float16* __restrict__ M2T) {
  const int n = blockIdx.x, t = threadIdx.x;
  __shared__ _Float16 sm[128 * 256];  // 64 KB
  const float* src = M2 + (size_t)n * 256 + t;
#pragma unroll 8
  for (int k = 0; k < 128; ++k)
    sm[k * 256 + t] = (_Float16)src[(size_t)k * 65536];
  __syncthreads();
  half2_t col[64];
#pragma unroll 16
  for (int k2 = 0; k2 < 64; ++k2)
    col[k2] = half2_t{sm[(2 * k2) * 256 + t], sm[(2 * k2 + 1) * 256 + t]};
  uint4* dst = (uint4*)(M2T + ((size_t)n * 256 + t) * 128);
  const uint4* s4 = (const uint4*)col;
#pragma unroll
  for (int i = 0; i < 16; ++i) dst[i] = s4[i];
}

// ---------------- mobility stage 2: MFMA GEMM + in-register softmax --------
// DE-SPILLED: one btile per wave. Rounds 3-6 used __launch_bounds__(512,2)
// (128-VGPR cap) with 128 f32 accumulators alive -> scratch spill (~150us
// hidden). Now C[16]=64 accs, ~150 live regs under a 256-VGPR cap.
// Wave-private LDS slot (row stride 264 to break write bank aliasing),
// no __syncthreads; Pi-mean partials re-derived from staged values.
#define MSLOT 264
__global__ __launch_bounds__(256, 2) void k_mobility2(
    const _Float16* __restrict__ hmf, const _Float16* __restrict__ M2T,
    const float* __restrict__ mb2, _Float16* __restrict__ PiF,
    float* __restrict__ pimpart) {
  const int n = blockIdx.x;
  const int tid = threadIdx.x;
  const int wave = tid >> 6, lane = tid & 63;
  const int q = lane >> 4, c = lane & 15;
  const int bt = blockIdx.y * 4 + wave;  // 0..31

  __shared__ _Float16 sm[4][16 * MSLOT];  // ~33 KB, wave-private slots

  const _Float16* Bbase = M2T + (size_t)n * 32768 + (size_t)c * 128 + q * 8;
  const float* mbp = mb2 + n * 256 + c;

  f32x4 C[16];
#pragma unroll
  for (int nb = 0; nb < 16; ++nb) {
    const float mbv = mbp[nb * 16];
    C[nb] = f32x4{mbv, mbv, mbv, mbv};
  }
  const _Float16* A0 = hmf + (size_t)(bt * 16 + c) * 128 + q * 8;
#pragma unroll
  for (int ks = 0; ks < 4; ++ks) {
    const f16x8 Af = *(const f16x8*)(A0 + ks * 32);
#pragma unroll
    for (int nb = 0; nb < 16; ++nb) {
      const f16x8 Bf = *(const f16x8*)(Bbase + nb * 2048 + ks * 32);
      C[nb] = __builtin_amdgcn_mfma_f32_16x16x32_f16(Af, Bf, C[nb], 0, 0, 0);
    }
  }

  // row softmax (row b = q*4+r, cols nb*16+c)
  float mx[4], sum[4];
#pragma unroll
  for (int r = 0; r < 4; ++r) mx[r] = C[0][r];
#pragma unroll
  for (int nb = 1; nb < 16; ++nb)
#pragma unroll
    for (int r = 0; r < 4; ++r) mx[r] = fmaxf(mx[r], C[nb][r]);
#pragma unroll
  for (int r = 0; r < 4; ++r) {
    mx[r] = fmaxf(mx[r], __shfl_xor(mx[r], 1, 16));
    mx[r] = fmaxf(mx[r], __shfl_xor(mx[r], 2, 16));
    mx[r] = fmaxf(mx[r], __shfl_xor(mx[r], 4, 16));
    mx[r] = fmaxf(mx[r], __shfl_xor(mx[r], 8, 16));
    sum[r] = 0.f;
  }
#pragma unroll
  for (int nb = 0; nb < 16; ++nb)
#pragma unroll
    for (int r = 0; r < 4; ++r) {
      const float e = __expf(C[nb][r] - mx[r]);
      C[nb][r] = e;
      sum[r] += e;
    }
#pragma unroll
  for (int r = 0; r < 4; ++r) {
    sum[r] += __shfl_xor(sum[r], 1, 16);
    sum[r] += __shfl_xor(sum[r], 2, 16);
    sum[r] += __shfl_xor(sum[r], 4, 16);
    sum[r] += __shfl_xor(sum[r], 8, 16);
    sum[r] = 1.f / sum[r];
  }

  // normalize + stage into wave-private slot
  _Float16* slot = sm[wave];
#pragma unroll
  for (int nb = 0; nb < 16; ++nb)
#pragma unroll
    for (int r = 0; r < 4; ++r)
      slot[(q * 4 + r) * MSLOT + nb * 16 + c] = (_Float16)(C[nb][r] * sum[r]);

  // coalesced store + Pi-mean column partials from the same reads
  const int l2 = lane & 31, rh = lane >> 5;
  _Float16* Pg = PiF + ((size_t)(bt * 16) * 256 + n) * 256;
  float cs[8] = {0.f, 0.f, 0.f, 0.f, 0.f, 0.f, 0.f, 0.f};
#pragma unroll
  for (int i = 0; i < 8; ++i) {
    const int row = i * 2 + rh;
    const uint4 v = *(const uint4*)(slot + row * MSLOT + l2 * 8);
    *(uint4*)(Pg + (size_t)row * 65536 + l2 * 8) = v;
    const f16x8 hv = __builtin_bit_cast(f16x8, v);
#pragma unroll
    for (int d = 0; d < 8; ++d) cs[d] += (float)hv[d];
  }
#pragma unroll
  for (int d = 0; d < 8; ++d) cs[d] += __shfl_xor(cs[d], 32);
  if (lane < 32) {
    float* pp = pimpart + n * 256 + l2 * 8;
#pragma unroll
    for (int d = 0; d < 8; ++d) atomicAdd(pp + d, cs[d]);
  }
}

// ---------------- means: scale stats + Pi-mean partials --------------------
__global__ __launch_bounds__(256) void k_finalize(
    const float* __restrict__ stats, const float* __restrict__ pimpart,
    float* __restrict__ out) {
  const int idx = blockIdx.x * 256 + threadIdx.x;
  const float inv = 1.f / 512.f;
  if (idx < 768) {
    out[3145728 + idx] = stats[idx] * inv;
  } else {
    const int pm = idx - 768;
    out[3146496 + pm] = pimpart[pm] * inv;
  }
}

// ---------------- SEIR RK4 simulation (MFMA force matvec) ------------------
__global__ __launch_bounds__(256, 2) void k_sim(
    const _Float16* __restrict__ PiF, const float* __restrict__ betaW,
    const float* __restrict__ sigmaW, const float* __restrict__ gammaW,
    const float* __restrict__ S0W, const float* __restrict__ E0W,
    const float* __restrict__ I0W, float* __restrict__ out) {
  const int b = blockIdx.x;
  const int tid = threadIdx.x;
  const int w = tid >> 6, lane = tid & 63;
  const int q = lane >> 4, c = lane & 15;
  const int mown = (4 * w + q) * 16 + c;

  __shared__ __align__(16) _Float16 Ib[2][256];

  f16x8 Bf[4][8];
  {
    const _Float16* P = PiF + (size_t)b * 65536 + (size_t)(q * 8) * 256 + c;
#pragma unroll
    for (int i = 0; i < 4; ++i) {
#pragma unroll
      for (int t = 0; t < 8; ++t) {
        const _Float16* src = P + (size_t)(t * 32) * 256 + (4 * w + i) * 16;
        f16x8 v;
#pragma unroll
        for (int j = 0; j < 8; ++j) v[j] = src[(size_t)j * 256];
        Bf[i][t] = v;
      }
    }
  }

  const int base = b * 256 + mown;
  const float bet = betaW[base], sig = sigmaW[base], gam = gammaW[base];
  float S = S0W[base], E = E0W[base], I = I0W[base];

  int p = 0;
  auto grads = [&](float Ss, float Es, float Is, float& dS, float& dE, float& dI) {
    Ib[p][mown] = (_Float16)Is;
    __syncthreads();
    const f16x8* ia = (const f16x8*)Ib[p];
    p ^= 1;
    f32x4 C[4];
#pragma unroll
    for (int i = 0; i < 4; ++i) C[i] = f32x4{0.f, 0.f, 0.f, 0.f};
#pragma unroll
    for (int t = 0; t < 8; ++t) {
      const f16x8 A = ia[t * 4 + q];
#pragma unroll
      for (int i = 0; i < 4; ++i)
        C[i] = __builtin_amdgcn_mfma_f32_16x16x32_f16(A, Bf[i][t], C[i], 0, 0, 0);
    }
    const float force = (q & 2) ? ((q & 1) ? C[3][0] : C[2][0])
                                : ((q & 1) ? C[1][0] : C[0][0]);
    const float ninf = bet * Ss * force;
    const float sE = sig * Es;
    dS = -ninf;
    dE = ninf - sE;
    dI = sE - gam * Is;
  };

  float* outI = out + (size_t)b * (12 * 256) + mown;
  float* outE = outI + 1572864;
  const float c6 = 0.25f / 6.f;

  for (int wk = 0; wk < 12; ++wk) {
    for (int st = 0; st < 4; ++st) {
      float d1S, d1E, d1I, d2S, d2E, d2I, d3S, d3E, d3I, d4S, d4E, d4I;
      grads(S, E, I, d1S, d1E, d1I);
      grads(S + 0.125f * d1S, E + 0.125f * d1E, I + 0.125f * d1I, d2S, d2E, d2I);
      grads(S + 0.125f * d2S, E + 0.125f * d2E, I + 0.125f * d2I, d3S, d3E, d3I);
      grads(S + 0.25f * d3S, E + 0.25f * d3E, I + 0.25f * d3I, d4S, d4E, d4I);
      S = fminf(fmaxf(S + c6 * (d1S + 2.f * d2S + 2.f * d3S + d4S), 0.f), 1.f);
      E = fminf(fmaxf(E + c6 * (d1E + 2.f * d2E + 2.f * d3E + d4E), 0.f), 1.f);
      I = fminf(fmaxf(I + c6 * (d1I + 2.f * d2I + 2.f * d3I + d4I), 0.f), 1.f);
    }
    outI[wk * 256] = I;
    outE[wk * 256] = E;
  }
}

// ---------------- launch ---------------------------------------------------
extern "C" void kernel_launch(void* const* d_in, const int* in_sizes, int n_in,
                              void* d_out, int out_size, void* d_ws, size_t ws_size,
                              hipStream_t stream) {
  const float* x_hist = (const float*)d_in[0];
  const float* cnn    = (const float*)d_in[1];
  const float* W1     = (const float*)d_in[2];
  const float* b1     = (const float*)d_in[3];
  const float* W2     = (const float*)d_in[4];
  const float* b2     = (const float*)d_in[5];
  const float* M1     = (const float*)d_in[6];
  const float* mb1    = (const float*)d_in[7];
  const float* M2     = (const float*)d_in[8];
  const float* mb2    = (const float*)d_in[9];
  float* out = (float*)d_out;

  char* w = (char*)d_ws;
  _Float16* M2T     = (_Float16*)(w + 0);         // 16,777,216
  _Float16* hmf     = (_Float16*)(w + 16777216);  //    131,072
  float*    betaW   = (float*)(w + 16908288);     //    524,288 each
  float*    sigmaW  = (float*)(w + 17432576);
  float*    gammaW  = (float*)(w + 17956864);
  float*    S0W     = (float*)(w + 18481152);
  float*    E0W     = (float*)(w + 19005440);
  float*    I0W     = (float*)(w + 19529728);
  float*    pimpart = (float*)(w + 20054016);     //    262,144
  float*    stats   = (float*)(w + 20316160);     //      4,096 (768 used)
  _Float16* PiF     = (_Float16*)(w + 20320256);  // 67,108,864 (end 87.4MB)
  // hpart aliases the PiF region (dead before k_mobility2 writes PiF)
  float*    hpart   = (float*)(w + 20320256);     //  8,388,608

  hipMemsetAsync(pimpart, 0, 266240, stream);  // pimpart + stats
  k_paramnet1<<<dim3(32, 16), 128, 0, stream>>>(x_hist, W1, hpart);
  k_params_state<<<256, 256, 0, stream>>>(hpart, b1, W2, b2, x_hist, betaW,
                                          sigmaW, gammaW, S0W, E0W, I0W, stats);
  k_mobility1<<<512, 128, 0, stream>>>(cnn, M1, mb1, hmf);
  k_cvtM2<<<256, 256, 0, stream>>>(M2, M2T);
  k_mobility2<<<dim3(256, 8), 256, 0, stream>>>(hmf, M2T, mb2, PiF, pimpart);
  k_finalize<<<259, 256, 0, stream>>>(stats, pimpart, out);
  k_sim<<<512, 256, 0, stream>>>(PiF, betaW, sigmaW, gammaW, S0W, E0W, I0W, out);
}

// Round 8
// 479.274 us; speedup vs baseline: 1.0933x; 1.0933x over previous
//
#include <hip/hip_runtime.h>
#include <hip/hip_bf16.h>
#include <stdint.h>
#include <stddef.h>

typedef _Float16 half2_t __attribute__((ext_vector_type(2)));
typedef _Float16 f16x8 __attribute__((ext_vector_type(8)));
typedef float f32x4 __attribute__((ext_vector_type(4)));

// ---------------- param_net stage 1: partial h = X @ W1 (K-split) ----------
__global__ __launch_bounds__(128) void k_paramnet1(
    const float* __restrict__ X, const float* __restrict__ W1,
    float* __restrict__ hpart) {
  const int j = threadIdx.x;
  const int ks = blockIdx.x;
  const int b0 = blockIdx.y * 32;

  float w1r[128];
#pragma unroll
  for (int k = 0; k < 128; ++k)
    w1r[k] = W1[(size_t)(ks * 128 + k) * 128 + j];

  for (int bb = 0; bb < 32; ++bb) {
    const float4* xr4 = (const float4*)(X + (size_t)(b0 + bb) * 4096 + ks * 128);
    float a0 = 0.f, a1 = 0.f, a2 = 0.f, a3 = 0.f;
#pragma unroll
    for (int k4 = 0; k4 < 32; ++k4) {
      const float4 xv = xr4[k4];
      a0 = fmaf(w1r[k4 * 4 + 0], xv.x, a0);
      a1 = fmaf(w1r[k4 * 4 + 1], xv.y, a1);
      a2 = fmaf(w1r[k4 * 4 + 2], xv.z, a2);
      a3 = fmaf(w1r[k4 * 4 + 3], xv.w, a3);
    }
    hpart[((size_t)ks * 512 + (b0 + bb)) * 128 + j] = (a0 + a1) + (a2 + a3);
  }
}

// ---- fused: h-reduce + relu + W2 matvec + sigmoids -> state + stat partials
__global__ __launch_bounds__(256) void k_params_state(
    const float* __restrict__ hpart, const float* __restrict__ b1,
    const float* __restrict__ W2, const float* __restrict__ b2,
    const float* __restrict__ X,
    float* __restrict__ betaW, float* __restrict__ sigmaW,
    float* __restrict__ gammaW, float* __restrict__ S0W,
    float* __restrict__ E0W, float* __restrict__ I0W,
    float* __restrict__ stats) {
  const int b0 = blockIdx.x * 2;
  const int t = threadIdx.x;
  __shared__ float hs[256];  // hs[bb*128 + j]
  {
    const int bb = t >> 7, j = t & 127;
    float s = b1[j];
    const float* hp = hpart + (size_t)(b0 + bb) * 128 + j;
#pragma unroll
    for (int ks = 0; ks < 32; ++ks) s += hp[(size_t)ks * 65536];
    hs[t] = fmaxf(s, 0.f);
  }
  __syncthreads();

  float a00 = b2[t], a01 = b2[256 + t], a02 = b2[512 + t], a03 = b2[768 + t];
  float a10 = a00, a11 = a01, a12 = a02, a13 = a03;
#pragma unroll 2
  for (int k = 0; k < 128; ++k) {
    const float* wr = W2 + (size_t)k * 1024;
    const float w0 = wr[t], w1 = wr[256 + t], w2 = wr[512 + t], w3 = wr[768 + t];
    const float hv0 = hs[k], hv1 = hs[128 + k];
    a00 = fmaf(hv0, w0, a00); a01 = fmaf(hv0, w1, a01);
    a02 = fmaf(hv0, w2, a02); a03 = fmaf(hv0, w3, a03);
    a10 = fmaf(hv1, w0, a10); a11 = fmaf(hv1, w1, a11);
    a12 = fmaf(hv1, w2, a12); a13 = fmaf(hv1, w3, a13);
  }
  float bsum = 0.f, ssum = 0.f, gsum = 0.f;
#pragma unroll
  for (int j = 0; j < 2; ++j) {
    const float p0 = j ? a10 : a00, p1 = j ? a11 : a01;
    const float p2 = j ? a12 : a02, p3 = j ? a13 : a03;
    const float beta = 3.f / (1.f + __expf(-p0));
    const float sig  = 1.f / (1.f + __expf(-p1));
    const float gam  = 1.f / (1.f + __expf(-p2));
    const float e0r  = 5.f / (1.f + __expf(-p3));
    const int base = (b0 + j) * 256 + t;
    const float I0 = fmaxf(X[(size_t)(b0 + j) * 4096 + 15 * 256 + t], 1e-6f);
    const float E0 = I0 * e0r;
    const float S0 = fmaxf(1.f - E0 - I0, 0.01f);
    betaW[base] = beta; sigmaW[base] = sig; gammaW[base] = gam;
    S0W[base] = S0; E0W[base] = E0; I0W[base] = I0;
    bsum += beta; ssum += sig; gsum += gam;
  }
  atomicAdd(stats + t, bsum);
  atomicAdd(stats + 256 + t, ssum);
  atomicAdd(stats + 512 + t, gsum);
}

// ---------------- mobility stage 1: hm = relu(cnn @ M1 + mb1) as f16 -------
__global__ __launch_bounds__(128) void k_mobility1(
    const float* __restrict__ cnn, const float* __restrict__ M1,
    const float* __restrict__ mb1, _Float16* __restrict__ hmf) {
  const int b = blockIdx.x, j = threadIdx.x;
  const float* cr = cnn + b * 64;
  float a = mb1[j];
#pragma unroll
  for (int k = 0; k < 64; ++k) a = fmaf(cr[k], M1[k * 128 + j], a);
  hmf[b * 128 + j] = (_Float16)fmaxf(a, 0.f);
}

// ---------------- transpose M2 -> M2T[n][m][k] f16, LDS-tiled --------------
__global__ __launch_bounds__(256) void k_cvtM2(
    const float* __restrict__ M2, _Float16* __restrict__ M2T) {
  const int n = blockIdx.x, t = threadIdx.x;
  __shared__ _Float16 sm[128 * 256];  // 64 KB
  const float* src = M2 + (size_t)n * 256 + t;
#pragma unroll 8
  for (int k = 0; k < 128; ++k)
    sm[k * 256 + t] = (_Float16)src[(size_t)k * 65536];
  __syncthreads();
  half2_t col[64];
#pragma unroll 16
  for (int k2 = 0; k2 < 64; ++k2)
    col[k2] = half2_t{sm[(2 * k2) * 256 + t], sm[(2 * k2 + 1) * 256 + t]};
  uint4* dst = (uint4*)(M2T + ((size_t)n * 256 + t) * 128);
  const uint4* s4 = (const uint4*)col;
#pragma unroll
  for (int i = 0; i < 16; ++i) dst[i] = s4[i];
}

// ---------------- mobility stage 2: MFMA GEMM + in-register softmax --------
// Round-6 structure (B-frags shared by two btiles, one output pass) but
// __launch_bounds__(512,1): C0[16]+C1[16] alone are 128 f32 accumulators,
// so the old (512,2) 128-VGPR cap forced scratch spill (rounds 3-6).
// ~160 live regs now fit the 256-VGPR cap (2 waves/SIMD). No atomics:
// Pi-mean is recomputed from PiF by k_finalize.
__global__ __launch_bounds__(512, 1) void k_mobility2(
    const _Float16* __restrict__ hmf, const _Float16* __restrict__ M2T,
    const float* __restrict__ mb2, _Float16* __restrict__ PiF) {
  const int n = blockIdx.x;
  const int pass = blockIdx.y;
  const int tid = threadIdx.x;
  const int wave = tid >> 6;
  const int lane = tid & 63;
  const int q = lane >> 4;
  const int c = lane & 15;

  __shared__ _Float16 sm[8][16 * 256];  // 64 KB, wave-private slots

  const _Float16* Bbase = M2T + (size_t)n * 32768 + (size_t)c * 128 + q * 8;
  const float* mbp = mb2 + n * 256 + c;

  const int bt0 = wave * 4 + pass * 2;
  f32x4 C0[16], C1[16];
#pragma unroll
  for (int nb = 0; nb < 16; ++nb) {
    const float mbv = mbp[nb * 16];
    C0[nb] = f32x4{mbv, mbv, mbv, mbv};
    C1[nb] = C0[nb];
  }
  const _Float16* A0 = hmf + (size_t)(bt0 * 16 + c) * 128 + q * 8;
  const _Float16* A1 = A0 + 16 * 128;
#pragma unroll
  for (int ks = 0; ks < 4; ++ks) {
    const f16x8 Af0 = *(const f16x8*)(A0 + ks * 32);
    const f16x8 Af1 = *(const f16x8*)(A1 + ks * 32);
#pragma unroll
    for (int nb = 0; nb < 16; ++nb) {
      const f16x8 Bf = *(const f16x8*)(Bbase + nb * 2048 + ks * 32);
      C0[nb] = __builtin_amdgcn_mfma_f32_16x16x32_f16(Af0, Bf, C0[nb], 0, 0, 0);
      C1[nb] = __builtin_amdgcn_mfma_f32_16x16x32_f16(Af1, Bf, C1[nb], 0, 0, 0);
    }
  }

#pragma unroll
  for (int half = 0; half < 2; ++half) {
    f32x4* C = half ? C1 : C0;
    const int bt = bt0 + half;
    float mx[4], sum[4];
#pragma unroll
    for (int r = 0; r < 4; ++r) mx[r] = C[0][r];
#pragma unroll
    for (int nb = 1; nb < 16; ++nb)
#pragma unroll
      for (int r = 0; r < 4; ++r) mx[r] = fmaxf(mx[r], C[nb][r]);
#pragma unroll
    for (int r = 0; r < 4; ++r) {
      mx[r] = fmaxf(mx[r], __shfl_xor(mx[r], 1, 16));
      mx[r] = fmaxf(mx[r], __shfl_xor(mx[r], 2, 16));
      mx[r] = fmaxf(mx[r], __shfl_xor(mx[r], 4, 16));
      mx[r] = fmaxf(mx[r], __shfl_xor(mx[r], 8, 16));
      sum[r] = 0.f;
    }
#pragma unroll
    for (int nb = 0; nb < 16; ++nb)
#pragma unroll
      for (int r = 0; r < 4; ++r) {
        const float e = __expf(C[nb][r] - mx[r]);
        C[nb][r] = e;
        sum[r] += e;
      }
#pragma unroll
    for (int r = 0; r < 4; ++r) {
      sum[r] += __shfl_xor(sum[r], 1, 16);
      sum[r] += __shfl_xor(sum[r], 2, 16);
      sum[r] += __shfl_xor(sum[r], 4, 16);
      sum[r] += __shfl_xor(sum[r], 8, 16);
      sum[r] = 1.f / sum[r];
    }
    _Float16* slot = sm[wave];
#pragma unroll
    for (int nb = 0; nb < 16; ++nb)
#pragma unroll
      for (int r = 0; r < 4; ++r)
        slot[(q * 4 + r) * 256 + nb * 16 + c] = (_Float16)(C[nb][r] * sum[r]);
    const int l2 = lane & 31, rh = lane >> 5;
    _Float16* Pg = PiF + ((size_t)(bt * 16) * 256 + n) * 256;
#pragma unroll
    for (int i = 0; i < 8; ++i) {
      const int row = i * 2 + rh;
      const uint4 v = *(const uint4*)(slot + row * 256 + l2 * 8);
      *(uint4*)(Pg + (size_t)row * 65536 + l2 * 8) = v;
    }
  }
}

// ---------------- means: stats scale + Pi-mean straight from PiF -----------
__global__ __launch_bounds__(256) void k_finalize(
    const float* __restrict__ stats, const _Float16* __restrict__ PiF,
    float* __restrict__ out) {
  const int blk = blockIdx.x;
  const float inv = 1.f / 512.f;
  if (blk < 256) {
    const int n = blk, m = threadIdx.x;
    const _Float16* p = PiF + (size_t)n * 256 + m;
    float s = 0.f;
#pragma unroll 8
    for (int b = 0; b < 512; ++b) s += (float)p[(size_t)b * 65536];
    out[3146496 + n * 256 + m] = s * inv;
  } else {
    const int idx = (blk - 256) * 256 + threadIdx.x;
    if (idx < 768) out[3145728 + idx] = stats[idx] * inv;
  }
}

// ---------------- SEIR RK4 simulation (MFMA force matvec) ------------------
__global__ __launch_bounds__(256, 2) void k_sim(
    const _Float16* __restrict__ PiF, const float* __restrict__ betaW,
    const float* __restrict__ sigmaW, const float* __restrict__ gammaW,
    const float* __restrict__ S0W, const float* __restrict__ E0W,
    const float* __restrict__ I0W, float* __restrict__ out) {
  const int b = blockIdx.x;
  const int tid = threadIdx.x;
  const int w = tid >> 6, lane = tid & 63;
  const int q = lane >> 4, c = lane & 15;
  const int mown = (4 * w + q) * 16 + c;

  __shared__ __align__(16) _Float16 Ib[2][256];

  f16x8 Bf[4][8];
  {
    const _Float16* P = PiF + (size_t)b * 65536 + (size_t)(q * 8) * 256 + c;
#pragma unroll
    for (int i = 0; i < 4; ++i) {
#pragma unroll
      for (int t = 0; t < 8; ++t) {
        const _Float16* src = P + (size_t)(t * 32) * 256 + (4 * w + i) * 16;
        f16x8 v;
#pragma unroll
        for (int j = 0; j < 8; ++j) v[j] = src[(size_t)j * 256];
        Bf[i][t] = v;
      }
    }
  }

  const int base = b * 256 + mown;
  const float bet = betaW[base], sig = sigmaW[base], gam = gammaW[base];
  float S = S0W[base], E = E0W[base], I = I0W[base];

  int p = 0;
  auto grads = [&](float Ss, float Es, float Is, float& dS, float& dE, float& dI) {
    Ib[p][mown] = (_Float16)Is;
    __syncthreads();
    const f16x8* ia = (const f16x8*)Ib[p];
    p ^= 1;
    f32x4 C[4];
#pragma unroll
    for (int i = 0; i < 4; ++i) C[i] = f32x4{0.f, 0.f, 0.f, 0.f};
#pragma unroll
    for (int t = 0; t < 8; ++t) {
      const f16x8 A = ia[t * 4 + q];
#pragma unroll
      for (int i = 0; i < 4; ++i)
        C[i] = __builtin_amdgcn_mfma_f32_16x16x32_f16(A, Bf[i][t], C[i], 0, 0, 0);
    }
    const float force = (q & 2) ? ((q & 1) ? C[3][0] : C[2][0])
                                : ((q & 1) ? C[1][0] : C[0][0]);
    const float ninf = bet * Ss * force;
    const float sE = sig * Es;
    dS = -ninf;
    dE = ninf - sE;
    dI = sE - gam * Is;
  };

  float* outI = out + (size_t)b * (12 * 256) + mown;
  float* outE = outI + 1572864;
  const float c6 = 0.25f / 6.f;

  for (int wk = 0; wk < 12; ++wk) {
    for (int st = 0; st < 4; ++st) {
      float d1S, d1E, d1I, d2S, d2E, d2I, d3S, d3E, d3I, d4S, d4E, d4I;
      grads(S, E, I, d1S, d1E, d1I);
      grads(S + 0.125f * d1S, E + 0.125f * d1E, I + 0.125f * d1I, d2S, d2E, d2I);
      grads(S + 0.125f * d2S, E + 0.125f * d2E, I + 0.125f * d2I, d3S, d3E, d3I);
      grads(S + 0.25f * d3S, E + 0.25f * d3E, I + 0.25f * d3I, d4S, d4E, d4I);
      S = fminf(fmaxf(S + c6 * (d1S + 2.f * d2S + 2.f * d3S + d4S), 0.f), 1.f);
      E = fminf(fmaxf(E + c6 * (d1E + 2.f * d2E + 2.f * d3E + d4E), 0.f), 1.f);
      I = fminf(fmaxf(I + c6 * (d1I + 2.f * d2I + 2.f * d3I + d4I), 0.f), 1.f);
    }
    outI[wk * 256] = I;
    outE[wk * 256] = E;
  }
}

// ---------------- launch ---------------------------------------------------
extern "C" void kernel_launch(void* const* d_in, const int* in_sizes, int n_in,
                              void* d_out, int out_size, void* d_ws, size_t ws_size,
                              hipStream_t stream) {
  const float* x_hist = (const float*)d_in[0];
  const float* cnn    = (const float*)d_in[1];
  const float* W1     = (const float*)d_in[2];
  const float* b1     = (const float*)d_in[3];
  const float* W2     = (const float*)d_in[4];
  const float* b2     = (const float*)d_in[5];
  const float* M1     = (const float*)d_in[6];
  const float* mb1    = (const float*)d_in[7];
  const float* M2     = (const float*)d_in[8];
  const float* mb2    = (const float*)d_in[9];
  float* out = (float*)d_out;

  char* w = (char*)d_ws;
  _Float16* M2T     = (_Float16*)(w + 0);         // 16,777,216
  _Float16* hmf     = (_Float16*)(w + 16777216);  //    131,072
  float*    betaW   = (float*)(w + 16908288);     //    524,288 each
  float*    sigmaW  = (float*)(w + 17432576);
  float*    gammaW  = (float*)(w + 17956864);
  float*    S0W     = (float*)(w + 18481152);
  float*    E0W     = (float*)(w + 19005440);
  float*    I0W     = (float*)(w + 19529728);
  float*    stats   = (float*)(w + 20054016);     //      4,096 (768 used)
  _Float16* PiF     = (_Float16*)(w + 20058112);  // 67,108,864 (end 87.2MB)
  // hpart aliases the PiF region (dead before k_mobility2 writes PiF)
  float*    hpart   = (float*)(w + 20058112);     //  8,388,608

  hipMemsetAsync(stats, 0, 4096, stream);
  k_paramnet1<<<dim3(32, 16), 128, 0, stream>>>(x_hist, W1, hpart);
  k_params_state<<<256, 256, 0, stream>>>(hpart, b1, W2, b2, x_hist, betaW,
                                          sigmaW, gammaW, S0W, E0W, I0W, stats);
  k_mobility1<<<512, 128, 0, stream>>>(cnn, M1, mb1, hmf);
  k_cvtM2<<<256, 256, 0, stream>>>(M2, M2T);
  k_mobility2<<<dim3(256, 2), 512, 0, stream>>>(hmf, M2T, mb2, PiF);
  k_finalize<<<259, 256, 0, stream>>>(stats, PiF, out);
  k_sim<<<512, 256, 0, stream>>>(PiF, betaW, sigmaW, gammaW, S0W, E0W, I0W, out);
}